// Round 1
// baseline (484.093 us; speedup 1.0000x reference)
//
#include <hip/hip_runtime.h>
#include <hip/hip_bf16.h>
#include <stdint.h>
#include <math.h>

#define NODES 8192
#define EDGES 4096
#define DIM   128
#define HID   256
#define NHEADS 4

using bf8   = __attribute__((ext_vector_type(8))) short;
using f32x4 = __attribute__((ext_vector_type(4))) float;
using i32x4 = __attribute__((ext_vector_type(4))) int;
using s16x4 = __attribute__((ext_vector_type(4))) short;

__device__ __forceinline__ short f2bf(float f) {
    uint32_t u = __float_as_uint(f);
    u += 0x7fffu + ((u >> 16) & 1u);   // RNE
    return (short)(u >> 16);
}
__device__ __forceinline__ float bf2f(short s) {
    return __uint_as_float(((uint32_t)(unsigned short)s) << 16);
}

// ---- transpose+convert edge_features [4096][128] f32 -> efT [128][4096] bf16
__global__ __launch_bounds__(256) void k_prep_ef(const float* __restrict__ ef, short* __restrict__ efT) {
    __shared__ float tile[32][33];
    int k0 = blockIdx.x * 32, c0 = blockIdx.y * 32;
    int t = threadIdx.x;
#pragma unroll
    for (int i = 0; i < 4; ++i) {
        int idx = t + i * 256;
        int kk = idx >> 5, cc = idx & 31;
        tile[kk][cc] = ef[(size_t)(k0 + kk) * DIM + c0 + cc];
    }
    __syncthreads();
#pragma unroll
    for (int i = 0; i < 4; ++i) {
        int idx = t + i * 256;
        int cc = idx >> 5, kk = idx & 31;
        efT[(size_t)(c0 + cc) * EDGES + k0 + kk] = f2bf(tile[kk][cc]);
    }
}

// ---- node_features f32 -> bf16
__global__ __launch_bounds__(256) void k_prep_x(const float* __restrict__ xf, short* __restrict__ xb) {
    int i = blockIdx.x * 256 + threadIdx.x;   // float4 index, 262144 total
    f32x4 v = *((const f32x4*)xf + i);
    s16x4 o;
#pragma unroll
    for (int j = 0; j < 4; ++j) o[j] = f2bf(v[j]);
    *((s16x4*)xb + i) = o;
}

// ---- fused weights A1T = (Wn@Wo)^T, A2T = (We@Wo)^T  (bf16, [h][n][k] layout)
__global__ __launch_bounds__(256) void k_w(const float* __restrict__ Wn, const float* __restrict__ We,
                                           const float* __restrict__ Wo,
                                           short* __restrict__ A1T, short* __restrict__ A2T) {
    int h = blockIdx.x >> 7, j = blockIdx.x & 127;
    int t = threadIdx.x;
    int k = t & 127;
    const float* W = (t < 128) ? Wn : We;
    const float* wrow = W + ((size_t)h * DIM * HID + (size_t)k * HID);
    const float* wocol = Wo + ((size_t)h * HID * DIM + j);
    float acc = 0.f;
    for (int m = 0; m < HID; ++m) acc += wrow[m] * wocol[(size_t)m * DIM];
    short* dst = (t < 128) ? A1T : A2T;
    dst[(size_t)h * DIM * DIM + (size_t)j * DIM + k] = f2bf(acc);
}

// ---- fused vectors v1=Wn@Wa, v2=We@Wa (f32), u1=bn@Wo+bo, u2=be@Wo, c1=bn@Wa+ba, c2=be@Wa
__global__ __launch_bounds__(256) void k_wv(const float* __restrict__ Wn, const float* __restrict__ We,
        const float* __restrict__ Wa, const float* __restrict__ bn, const float* __restrict__ be,
        const float* __restrict__ ba, const float* __restrict__ Wo, const float* __restrict__ bo,
        float* __restrict__ v1, float* __restrict__ v2, float* __restrict__ u1, float* __restrict__ u2,
        float* __restrict__ cc) {
    int h = blockIdx.x, t = threadIdx.x;
    const float* wa = Wa + (size_t)h * HID;
    if (t < 128) {
        int k = t;
        const float* wr = Wn + (size_t)h * DIM * HID + (size_t)k * HID;
        float a = 0.f;
        for (int m = 0; m < HID; ++m) a += wr[m] * wa[m];
        v1[h * DIM + k] = a;
        const float* bnr = bn + (size_t)h * HID;
        const float* wo = Wo + (size_t)h * HID * DIM + k;
        float b = 0.f;
        for (int m = 0; m < HID; ++m) b += bnr[m] * wo[(size_t)m * DIM];
        u1[h * DIM + k] = b + bo[h * DIM + k];
        if (k == 0) { float c = 0.f; for (int m = 0; m < HID; ++m) c += bnr[m] * wa[m]; cc[h * 2 + 0] = c + ba[h]; }
    } else {
        int k = t - 128;
        const float* wr = We + (size_t)h * DIM * HID + (size_t)k * HID;
        float a = 0.f;
        for (int m = 0; m < HID; ++m) a += wr[m] * wa[m];
        v2[h * DIM + k] = a;
        const float* ber = be + (size_t)h * HID;
        const float* wo = Wo + (size_t)h * HID * DIM + k;
        float b = 0.f;
        for (int m = 0; m < HID; ++m) b += ber[m] * wo[(size_t)m * DIM];
        u2[h * DIM + k] = b;
        if (k == 0) { float c = 0.f; for (int m = 0; m < HID; ++m) c += ber[m] * wa[m]; cc[h * 2 + 1] = c; }
    }
}

// ---- the big one: P = incidence @ ef  (bf16 MFMA, fp32 acc) + rowsum(incidence)
// M-tile 16, N=128, K-chunk 64; grid 512 blocks x 256 threads (4 waves, 32 cols each)
__global__ __launch_bounds__(256) void k1_pgemm(const float* __restrict__ inc, const short* __restrict__ efT,
        float* __restrict__ P, short* __restrict__ Pbf,
        float* __restrict__ rowsum, float* __restrict__ invdeg) {
    __shared__ short lds_a[16][72];     // [m][k] bf16, pad to 72
    __shared__ short lds_b[128][72];    // [n][k] bf16
    const int t = threadIdx.x;
    const int m0 = blockIdx.x * 16;
    const int w = t >> 6, l = t & 63, q = l >> 4, lr = l & 15;
    const int arow = t >> 3;            // t<128: 0..15
    const int akc  = (t & 7) * 8;
    float degp = 0.f;
    f32x4 acc[2] = {{0.f, 0.f, 0.f, 0.f}, {0.f, 0.f, 0.f, 0.f}};
    f32x4 pa0 = {0.f, 0.f, 0.f, 0.f}, pa1 = {0.f, 0.f, 0.f, 0.f};
    i32x4 pbv[4];
    const float* aptr = inc + (size_t)(m0 + (arow & 15)) * EDGES + akc;

    // prefetch k0 = 0
    if (t < 128) { pa0 = *(const f32x4*)aptr; pa1 = *(const f32x4*)(aptr + 4); }
#pragma unroll
    for (int i = 0; i < 4; ++i) {
        int idx = t + i * 256; int nr = idx >> 3, c = idx & 7;
        pbv[i] = *(const i32x4*)&efT[(size_t)nr * EDGES + c * 8];
    }

    for (int it = 0; it < 64; ++it) {
        __syncthreads();
        if (t < 128) {
            bf8 pk;
#pragma unroll
            for (int j = 0; j < 4; ++j) {
                pk[j]     = f2bf(pa0[j]);
                pk[4 + j] = f2bf(pa1[j]);
                degp += pa0[j] + pa1[j];
            }
            *(bf8*)&lds_a[arow][akc] = pk;
        }
#pragma unroll
        for (int i = 0; i < 4; ++i) {
            int idx = t + i * 256; int nr = idx >> 3, c = idx & 7;
            *(i32x4*)&lds_b[nr][c * 8] = pbv[i];
        }
        __syncthreads();
        if (it < 63) {
            int k0 = (it + 1) * 64;
            if (t < 128) { pa0 = *(const f32x4*)(aptr + k0); pa1 = *(const f32x4*)(aptr + k0 + 4); }
#pragma unroll
            for (int i = 0; i < 4; ++i) {
                int idx = t + i * 256; int nr = idx >> 3, c = idx & 7;
                pbv[i] = *(const i32x4*)&efT[(size_t)nr * EDGES + k0 + c * 8];
            }
        }
#pragma unroll
        for (int kk = 0; kk < 64; kk += 32) {
            bf8 af = *(bf8*)&lds_a[lr][kk + q * 8];
#pragma unroll
            for (int nf = 0; nf < 2; ++nf) {
                bf8 bfr = *(bf8*)&lds_b[w * 32 + nf * 16 + lr][kk + q * 8];
                acc[nf] = __builtin_amdgcn_mfma_f32_16x16x32_bf16(af, bfr, acc[nf], 0, 0, 0);
            }
        }
    }
    // rowsum reduce across the 8 k-slice threads per row
    float rs = degp;
    rs += __shfl_xor(rs, 1);
    rs += __shfl_xor(rs, 2);
    rs += __shfl_xor(rs, 4);
    if (t < 128 && (t & 7) == 0) {
        int row = m0 + arow;
        rowsum[row] = rs;
        invdeg[row] = 1.f / (rs + 1e-8f);
    }
#pragma unroll
    for (int nf = 0; nf < 2; ++nf) {
        int col = w * 32 + nf * 16 + lr;
#pragma unroll
        for (int r = 0; r < 4; ++r) {
            int row = m0 + q * 4 + r;
            float v = acc[nf][r];
            P[(size_t)row * DIM + col] = v;
            Pbf[(size_t)row * DIM + col] = f2bf(v);
        }
    }
}

// ---- per-head attention coefficient: coeff = sigmoid(leaky_relu(x.v1 + invdeg*(P.v2 + rs*c2) + c1))
__global__ __launch_bounds__(256) void k_score(const short* __restrict__ xb, const float* __restrict__ P,
        const float* __restrict__ v1, const float* __restrict__ v2, const float* __restrict__ cc,
        const float* __restrict__ invdeg, const float* __restrict__ rowsum, float* __restrict__ coeff) {
    int t = threadIdx.x, w = t >> 6, l = t & 63;
    int gw = blockIdx.x * 4 + w;
    float v1a = v1[l], v1b = v1[64 + l], v2a = v2[l], v2b = v2[64 + l];
    float c1 = cc[0], c2 = cc[1];
    for (int row = gw; row < NODES; row += 256) {
        const short* xr = xb + (size_t)row * DIM;
        const float* pr = P + (size_t)row * DIM;
        float id = invdeg[row];
        float s = bf2f(xr[l]) * v1a + bf2f(xr[64 + l]) * v1b + (pr[l] * v2a + pr[64 + l] * v2b) * id;
#pragma unroll
        for (int off = 32; off; off >>= 1) s += __shfl_xor(s, off);
        if (l == 0) {
            float sc = s + c1 + rowsum[row] * c2 * id;
            sc = sc > 0.f ? sc : 0.2f * sc;
            coeff[row] = 1.f / (1.f + __expf(-sc));
        }
    }
}

// ---- per-head output: out = x@A1 + cf*(P@A2) + u1 + cf*rs*u2,  cf = coeff*invdeg
__global__ __launch_bounds__(256) void k_out(const short* __restrict__ xb, const short* __restrict__ Pbf,
        const short* __restrict__ W1, const short* __restrict__ W2,
        const float* __restrict__ coeff, const float* __restrict__ invdeg, const float* __restrict__ rowsum,
        const float* __restrict__ u1, const float* __restrict__ u2, float* __restrict__ outp) {
    __shared__ short lx[16][136];
    __shared__ short lp[16][136];
    __shared__ short lw1[128][136];
    __shared__ short lw2[128][136];
    int t = threadIdx.x, m0 = blockIdx.x * 16;
    int w = t >> 6, l = t & 63, q = l >> 4, lr = l & 15;
    {
        int row = t >> 4, c = (t & 15) * 8;
        *(i32x4*)&lx[row][c] = *(const i32x4*)&xb[(size_t)(m0 + row) * DIM + c];
        *(i32x4*)&lp[row][c] = *(const i32x4*)&Pbf[(size_t)(m0 + row) * DIM + c];
    }
#pragma unroll
    for (int i = 0; i < 8; ++i) {
        int idx = t + i * 256;
        int nr = idx >> 4, c = (idx & 15) * 8;
        *(i32x4*)&lw1[nr][c] = *(const i32x4*)&W1[(size_t)nr * DIM + c];
        *(i32x4*)&lw2[nr][c] = *(const i32x4*)&W2[(size_t)nr * DIM + c];
    }
    __syncthreads();
    f32x4 a1[2] = {{0.f, 0.f, 0.f, 0.f}, {0.f, 0.f, 0.f, 0.f}};
    f32x4 a2[2] = {{0.f, 0.f, 0.f, 0.f}, {0.f, 0.f, 0.f, 0.f}};
#pragma unroll
    for (int kk = 0; kk < 128; kk += 32) {
        bf8 xa = *(bf8*)&lx[lr][kk + q * 8];
        bf8 pa = *(bf8*)&lp[lr][kk + q * 8];
#pragma unroll
        for (int nf = 0; nf < 2; ++nf) {
            bf8 b1 = *(bf8*)&lw1[w * 32 + nf * 16 + lr][kk + q * 8];
            bf8 b2 = *(bf8*)&lw2[w * 32 + nf * 16 + lr][kk + q * 8];
            a1[nf] = __builtin_amdgcn_mfma_f32_16x16x32_bf16(xa, b1, a1[nf], 0, 0, 0);
            a2[nf] = __builtin_amdgcn_mfma_f32_16x16x32_bf16(pa, b2, a2[nf], 0, 0, 0);
        }
    }
    float u1a[2], u2a[2];
    u1a[0] = u1[w * 32 + lr];      u1a[1] = u1[w * 32 + 16 + lr];
    u2a[0] = u2[w * 32 + lr];      u2a[1] = u2[w * 32 + 16 + lr];
#pragma unroll
    for (int r = 0; r < 4; ++r) {
        int row = m0 + q * 4 + r;
        float cf = coeff[row] * invdeg[row];
        float su = rowsum[row] * cf;
#pragma unroll
        for (int nf = 0; nf < 2; ++nf) {
            int col = w * 32 + nf * 16 + lr;
            outp[(size_t)row * DIM + col] = a1[nf][r] + cf * a2[nf][r] + u1a[nf] + su * u2a[nf];
        }
    }
}

// ---- column-wise partial min/max (64 blocks x 128 rows)
__global__ __launch_bounds__(128) void k_mm(const float* __restrict__ outp,
        float* __restrict__ pmin, float* __restrict__ pmax) {
    int j = threadIdx.x, r0 = blockIdx.x * 128;
    float mn = 1e30f, mx = -1e30f;
    for (int r = 0; r < 128; ++r) {
        float v = outp[(size_t)(r0 + r) * DIM + j];
        mn = fminf(mn, v); mx = fmaxf(mx, v);
    }
    pmin[blockIdx.x * DIM + j] = mn;
    pmax[blockIdx.x * DIM + j] = mx;
}

// ---- final reduce of partials + normalize (+relu); writes f32 (last head) or bf16 (next x)
__global__ __launch_bounds__(256) void k_norm(const float* __restrict__ outp, const float* __restrict__ pmin,
        const float* __restrict__ pmax, float* __restrict__ of, short* __restrict__ ob) {
    __shared__ float smn[128], srv[128];
    int t = threadIdx.x;
    if (t < 128) {
        float mn = 1e30f, mx = -1e30f;
        for (int b = 0; b < 64; ++b) {
            mn = fminf(mn, pmin[b * DIM + t]);
            mx = fmaxf(mx, pmax[b * DIM + t]);
        }
        smn[t] = mn;
        srv[t] = 1.f / (mx - mn + 1e-8f);
    }
    __syncthreads();
    int r0 = blockIdx.x * 128;
    for (int idx = t; idx < 128 * DIM; idx += 256) {
        int r = idx >> 7, j = idx & 127;
        float v = (outp[(size_t)(r0 + r) * DIM + j] - smn[j]) * srv[j];
        v = fmaxf(v, 0.f);
        if (of) of[(size_t)(r0 + r) * DIM + j] = v;
        else    ob[(size_t)(r0 + r) * DIM + j] = f2bf(v);
    }
}

extern "C" void kernel_launch(void* const* d_in, const int* in_sizes, int n_in,
                              void* d_out, int out_size, void* d_ws, size_t ws_size,
                              hipStream_t stream) {
    const float* nodef = (const float*)d_in[0];
    const float* inc   = (const float*)d_in[1];
    const float* ef    = (const float*)d_in[2];
    const float* Wn    = (const float*)d_in[3];
    const float* bn    = (const float*)d_in[4];
    const float* We    = (const float*)d_in[5];
    const float* be    = (const float*)d_in[6];
    const float* Wa    = (const float*)d_in[7];
    const float* ba    = (const float*)d_in[8];
    const float* Wo    = (const float*)d_in[9];
    const float* bo    = (const float*)d_in[10];

    char* ws = (char*)d_ws;
    float* P      = (float*)(ws + 0);
    float* outp   = (float*)(ws + 4194304);
    short* Pbf    = (short*)(ws + 8388608);
    short* xb0    = (short*)(ws + 10485760);
    short* xb1    = (short*)(ws + 12582912);
    short* efT    = (short*)(ws + 14680064);
    short* A1T    = (short*)(ws + 15728640);
    short* A2T    = (short*)(ws + 15859712);
    float* rowsum = (float*)(ws + 15990784);
    float* invdeg = (float*)(ws + 16023552);
    float* coeff  = (float*)(ws + 16056320);
    float* v1     = (float*)(ws + 16089088);
    float* v2     = (float*)(ws + 16091136);
    float* u1     = (float*)(ws + 16093184);
    float* u2     = (float*)(ws + 16095232);
    float* cc     = (float*)(ws + 16097280);
    float* pmin   = (float*)(ws + 16098304);
    float* pmax   = (float*)(ws + 16131072);

    hipLaunchKernelGGL(k_prep_ef, dim3(128, 4), dim3(256), 0, stream, ef, efT);
    hipLaunchKernelGGL(k_prep_x, dim3(1024), dim3(256), 0, stream, nodef, xb0);
    hipLaunchKernelGGL(k_w, dim3(512), dim3(256), 0, stream, Wn, We, Wo, A1T, A2T);
    hipLaunchKernelGGL(k_wv, dim3(4), dim3(256), 0, stream, Wn, We, Wa, bn, be, ba, Wo, bo,
                       v1, v2, u1, u2, cc);
    hipLaunchKernelGGL(k1_pgemm, dim3(512), dim3(256), 0, stream, inc, efT, P, Pbf, rowsum, invdeg);

    short* xcur = xb0; short* xnxt = xb1;
    for (int h = 0; h < NHEADS; ++h) {
        hipLaunchKernelGGL(k_score, dim3(64), dim3(256), 0, stream, xcur, P,
                           v1 + h * DIM, v2 + h * DIM, cc + h * 2, invdeg, rowsum, coeff);
        hipLaunchKernelGGL(k_out, dim3(512), dim3(256), 0, stream, xcur, Pbf,
                           A1T + (size_t)h * DIM * DIM, A2T + (size_t)h * DIM * DIM,
                           coeff, invdeg, rowsum, u1 + h * DIM, u2 + h * DIM, outp);
        hipLaunchKernelGGL(k_mm, dim3(64), dim3(128), 0, stream, outp, pmin, pmax);
        hipLaunchKernelGGL(k_norm, dim3(64), dim3(256), 0, stream, outp, pmin, pmax,
                           (h == NHEADS - 1) ? (float*)d_out : nullptr, xnxt);
        short* tmp = xcur; xcur = xnxt; xnxt = tmp;
    }
}

// Round 2
// 364.441 us; speedup vs baseline: 1.3283x; 1.3283x over previous
//
#include <hip/hip_runtime.h>
#include <hip/hip_bf16.h>
#include <stdint.h>
#include <math.h>

#define NODES 8192
#define EDGES 4096
#define DIM   128
#define HID   256
#define NHEADS 4

using bf8   = __attribute__((ext_vector_type(8))) short;
using f32x4 = __attribute__((ext_vector_type(4))) float;
using i32x4 = __attribute__((ext_vector_type(4))) int;
using s16x4 = __attribute__((ext_vector_type(4))) short;

__device__ __forceinline__ short f2bf(float f) {
    uint32_t u = __float_as_uint(f);
    u += 0x7fffu + ((u >> 16) & 1u);   // RNE
    return (short)(u >> 16);
}
__device__ __forceinline__ float bf2f(short s) {
    return __uint_as_float(((uint32_t)(unsigned short)s) << 16);
}
// order-preserving float<->uint key for atomic min/max
__device__ __forceinline__ unsigned fkey(float f) {
    unsigned u = __float_as_uint(f);
    return (u & 0x80000000u) ? ~u : (u | 0x80000000u);
}
__device__ __forceinline__ float fdec(unsigned k) {
    unsigned u = (k & 0x80000000u) ? (k & 0x7fffffffu) : ~k;
    return __uint_as_float(u);
}

// ---- transpose+convert edge_features [4096][128] f32 -> efT [128][4096] bf16
__global__ __launch_bounds__(256) void k_prep_ef(const float* __restrict__ ef, short* __restrict__ efT) {
    __shared__ float tile[32][33];
    int k0 = blockIdx.x * 32, c0 = blockIdx.y * 32;
    int t = threadIdx.x;
#pragma unroll
    for (int i = 0; i < 4; ++i) {
        int idx = t + i * 256;
        int kk = idx >> 5, cc = idx & 31;
        tile[kk][cc] = ef[(size_t)(k0 + kk) * DIM + c0 + cc];
    }
    __syncthreads();
#pragma unroll
    for (int i = 0; i < 4; ++i) {
        int idx = t + i * 256;
        int cc = idx >> 5, kk = idx & 31;
        efT[(size_t)(c0 + cc) * EDGES + k0 + kk] = f2bf(tile[kk][cc]);
    }
}

// ---- node_features f32 -> bf16; also init atomic min/max slots (4 heads x 128 cols)
__global__ __launch_bounds__(256) void k_prep_x(const float* __restrict__ xf, short* __restrict__ xb,
                                                unsigned* __restrict__ amin, unsigned* __restrict__ amax) {
    int i = blockIdx.x * 256 + threadIdx.x;   // float4 index, 262144 total
    f32x4 v = *((const f32x4*)xf + i);
    s16x4 o;
#pragma unroll
    for (int j = 0; j < 4; ++j) o[j] = f2bf(v[j]);
    *((s16x4*)xb + i) = o;
    if (blockIdx.x < 4 && threadIdx.x < 128) {
        amin[blockIdx.x * 128 + threadIdx.x] = 0xFFFFFFFFu;
        amax[blockIdx.x * 128 + threadIdx.x] = 0u;
    }
}

// ---- fused weights A1T = (Wn@Wo)^T, A2T = (We@Wo)^T (bf16 [h][j][k]); coalesced via LDS chunks
__global__ __launch_bounds__(256) void k_w(const float* __restrict__ Wn, const float* __restrict__ We,
                                           const float* __restrict__ Wo,
                                           short* __restrict__ A1T, short* __restrict__ A2T) {
    __shared__ float lw[2][128][17];
    int b = blockIdx.x, h = b >> 6, jj = b & 63;
    int t = threadIdx.x;
    int mat = t >> 7, k = t & 127;
    const float* WoH = Wo + (size_t)h * HID * DIM;
    float acc0 = 0.f, acc1 = 0.f;
    for (int mc = 0; mc < 16; ++mc) {
        __syncthreads();
#pragma unroll
        for (int i = 0; i < 4; ++i) {
            int u = t + i * 256;
            int m_ = u >> 9, kk2 = (u >> 2) & 127, qd = u & 3;
            const float* src = (m_ ? We : Wn) + (size_t)h * DIM * HID + (size_t)kk2 * HID + mc * 16 + qd * 4;
            f32x4 val = *(const f32x4*)src;
#pragma unroll
            for (int j2 = 0; j2 < 4; ++j2) lw[m_][kk2][qd * 4 + j2] = val[j2];
        }
        __syncthreads();
#pragma unroll
        for (int mm = 0; mm < 16; ++mm) {
            float a = lw[mat][k][mm];
            int m = mc * 16 + mm;
            acc0 += a * WoH[(size_t)m * DIM + jj];
            acc1 += a * WoH[(size_t)m * DIM + jj + 64];
        }
    }
    short* dst = mat ? A2T : A1T;
    dst[(size_t)h * DIM * DIM + (size_t)jj * DIM + k] = f2bf(acc0);
    dst[(size_t)h * DIM * DIM + (size_t)(jj + 64) * DIM + k] = f2bf(acc1);
}

// ---- fused vectors v1=Wn@Wa, v2=We@Wa, u1=bn@Wo+bo, u2=be@Wo, cc={bn@Wa+ba, be@Wa}
__global__ __launch_bounds__(256) void k_wv(const float* __restrict__ Wn, const float* __restrict__ We,
        const float* __restrict__ Wa, const float* __restrict__ bn, const float* __restrict__ be,
        const float* __restrict__ ba, const float* __restrict__ Wo, const float* __restrict__ bo,
        float* __restrict__ v1, float* __restrict__ v2, float* __restrict__ u1, float* __restrict__ u2,
        float* __restrict__ cc) {
    __shared__ float lw[2][128][17];
    int h = blockIdx.x, t = threadIdx.x;
    int mat = t >> 7, k = t & 127;
    const float* wa = Wa + (size_t)h * HID;
    float acc = 0.f;
    for (int mc = 0; mc < 16; ++mc) {
        __syncthreads();
#pragma unroll
        for (int i = 0; i < 4; ++i) {
            int u = t + i * 256;
            int m_ = u >> 9, kk2 = (u >> 2) & 127, qd = u & 3;
            const float* src = (m_ ? We : Wn) + (size_t)h * DIM * HID + (size_t)kk2 * HID + mc * 16 + qd * 4;
            f32x4 val = *(const f32x4*)src;
#pragma unroll
            for (int j2 = 0; j2 < 4; ++j2) lw[m_][kk2][qd * 4 + j2] = val[j2];
        }
        __syncthreads();
#pragma unroll
        for (int mm = 0; mm < 16; ++mm) acc += lw[mat][k][mm] * wa[mc * 16 + mm];
    }
    (mat ? v2 : v1)[h * DIM + k] = acc;
    const float* bias = (mat ? be : bn) + (size_t)h * HID;
    const float* WoH = Wo + (size_t)h * HID * DIM;
    float ua = 0.f;
    for (int m = 0; m < HID; ++m) ua += bias[m] * WoH[(size_t)m * DIM + k];
    if (mat) u2[h * DIM + k] = ua;
    else     u1[h * DIM + k] = ua + bo[h * DIM + k];
    if (t == 0)   { float c = 0.f; for (int m = 0; m < HID; ++m) c += bn[(size_t)h * HID + m] * wa[m]; cc[h * 2 + 0] = c + ba[h]; }
    if (t == 128) { float c = 0.f; for (int m = 0; m < HID; ++m) c += be[(size_t)h * HID + m] * wa[m]; cc[h * 2 + 1] = c; }
}

// ---- P = incidence @ ef : barrier-free register-fragment MFMA, M=32, K-split 2
// grid 512 = 256 Mtiles x 2 ksplits; 4 waves each own K=512; LDS only for final reduce.
__global__ __launch_bounds__(256) void k1_pgemm(const float* __restrict__ inc, const short* __restrict__ efT,
        float* __restrict__ Ppart, float* __restrict__ rspart) {
    __shared__ float red[2][32][129];
    __shared__ float rsl[4][2][16];
    const int t = threadIdx.x;
    const int w = t >> 6, l = t & 63, q = l >> 4, lr = l & 15;
    const int m0 = (blockIdx.x >> 1) * 32;
    const int ks = blockIdx.x & 1;
    const int kbase = ks * 2048 + w * 512;
    const float* a0p = inc + (size_t)(m0 + lr) * EDGES + kbase + q * 8;
    const float* a1p = a0p + (size_t)16 * EDGES;
    const short* bbase = efT + (size_t)lr * EDGES + kbase + q * 8;
    f32x4 acc[2][8];
#pragma unroll
    for (int f = 0; f < 2; ++f)
#pragma unroll
        for (int cb = 0; cb < 8; ++cb) acc[f][cb] = (f32x4){0.f, 0.f, 0.f, 0.f};
    float rs0 = 0.f, rs1 = 0.f;
    f32x4 an0 = *(const f32x4*)a0p, an1 = *(const f32x4*)(a0p + 4);
    f32x4 an2 = *(const f32x4*)a1p, an3 = *(const f32x4*)(a1p + 4);
    for (int s = 0; s < 16; ++s) {
        // B fragments for this step (L2-resident) — issue first
        bf8 bfr[8];
        const short* bp = bbase + s * 32;
#pragma unroll
        for (int cb = 0; cb < 8; ++cb) bfr[cb] = *(const bf8*)(bp + cb * 16 * EDGES);
        // convert current A (already in regs) + rowsum
        bf8 a0, a1;
#pragma unroll
        for (int j = 0; j < 4; ++j) {
            a0[j] = f2bf(an0[j]); a0[4 + j] = f2bf(an1[j]);
            a1[j] = f2bf(an2[j]); a1[4 + j] = f2bf(an3[j]);
            rs0 += an0[j] + an1[j];
            rs1 += an2[j] + an3[j];
        }
        // prefetch next A (HBM)
        if (s < 15) {
            const float* na = a0p + (s + 1) * 32;
            const float* nb = a1p + (s + 1) * 32;
            an0 = *(const f32x4*)na; an1 = *(const f32x4*)(na + 4);
            an2 = *(const f32x4*)nb; an3 = *(const f32x4*)(nb + 4);
        }
#pragma unroll
        for (int cb = 0; cb < 8; ++cb) {
            acc[0][cb] = __builtin_amdgcn_mfma_f32_16x16x32_bf16(a0, bfr[cb], acc[0][cb], 0, 0, 0);
            acc[1][cb] = __builtin_amdgcn_mfma_f32_16x16x32_bf16(a1, bfr[cb], acc[1][cb], 0, 0, 0);
        }
    }
    // rowsum reduce across q-groups (lanes l, l^16, l^32 share lr)
    rs0 += __shfl_xor(rs0, 16); rs0 += __shfl_xor(rs0, 32);
    rs1 += __shfl_xor(rs1, 16); rs1 += __shfl_xor(rs1, 32);
    if (l < 16) { rsl[w][0][lr] = rs0; rsl[w][1][lr] = rs1; }
    if (w < 2) {
#pragma unroll
        for (int f = 0; f < 2; ++f)
#pragma unroll
            for (int cb = 0; cb < 8; ++cb)
#pragma unroll
                for (int r = 0; r < 4; ++r)
                    red[w][f * 16 + q * 4 + r][cb * 16 + lr] = acc[f][cb][r];
    }
    __syncthreads();
    if (w >= 2) {
#pragma unroll
        for (int f = 0; f < 2; ++f)
#pragma unroll
            for (int cb = 0; cb < 8; ++cb)
#pragma unroll
                for (int r = 0; r < 4; ++r)
                    red[w - 2][f * 16 + q * 4 + r][cb * 16 + lr] += acc[f][cb][r];
    }
    __syncthreads();
    float* gp = Ppart + (size_t)ks * (NODES * DIM) + (size_t)m0 * DIM;
#pragma unroll
    for (int i = 0; i < 16; ++i) {
        int e = t + i * 256;
        int row = e >> 7, col = e & 127;
        gp[(size_t)row * DIM + col] = red[0][row][col] + red[1][row][col];
    }
    if (t < 32) {
        int f = t >> 4, r = t & 15;
        rspart[ks * NODES + m0 + f * 16 + r] = rsl[0][f][r] + rsl[1][f][r] + rsl[2][f][r] + rsl[3][f][r];
    }
}

// ---- per-head fused: normalize prev output -> x, score+coeff, out GEMM, column min/max atomics
__global__ __launch_bounds__(256) void k_out(
        const short* __restrict__ xb,      // head 0 input (bf16) or nullptr
        const float* xf,                   // heads>=1: prev outp f32 (aliases outw!)
        const float* __restrict__ smn, const float* __restrict__ srv,
        const float* __restrict__ Pp, const float* __restrict__ rsp,
        const short* __restrict__ W1, const short* __restrict__ W2,
        const float* __restrict__ v1, const float* __restrict__ v2,
        const float* __restrict__ cc, const float* __restrict__ u1, const float* __restrict__ u2,
        unsigned* __restrict__ amin, unsigned* __restrict__ amax,
        float* outw) {
    __shared__ short lx[16][136];
    __shared__ short lp[16][136];
    __shared__ short lw1[128][136];
    __shared__ short lw2[128][136];
    __shared__ float sv1[128], sv2[128], rsL[16], idL[16], coL[16];
    int t = threadIdx.x, m0 = blockIdx.x * 16;
    int w = t >> 6, l = t & 63, q = l >> 4, lr = l & 15;
    {
        int row = t >> 4, c = (t & 15) * 8;
        if (xb) {
            *(i32x4*)&lx[row][c] = *(const i32x4*)&xb[(size_t)(m0 + row) * DIM + c];
        } else {
            f32x4 x0 = *(const f32x4*)&xf[(size_t)(m0 + row) * DIM + c];
            f32x4 x1 = *(const f32x4*)&xf[(size_t)(m0 + row) * DIM + c + 4];
            f32x4 mn0 = *(const f32x4*)&smn[c], mn1 = *(const f32x4*)&smn[c + 4];
            f32x4 rv0 = *(const f32x4*)&srv[c], rv1 = *(const f32x4*)&srv[c + 4];
            bf8 pk;
#pragma unroll
            for (int j = 0; j < 4; ++j) {
                pk[j]     = f2bf(fmaxf((x0[j] - mn0[j]) * rv0[j], 0.f));
                pk[4 + j] = f2bf(fmaxf((x1[j] - mn1[j]) * rv1[j], 0.f));
            }
            *(bf8*)&lx[row][c] = pk;
        }
        f32x4 p0 = *(const f32x4*)&Pp[(size_t)(m0 + row) * DIM + c];
        f32x4 p1 = *(const f32x4*)&Pp[(size_t)(m0 + row) * DIM + c + 4];
        f32x4 q0 = *(const f32x4*)&Pp[(size_t)NODES * DIM + (size_t)(m0 + row) * DIM + c];
        f32x4 q1 = *(const f32x4*)&Pp[(size_t)NODES * DIM + (size_t)(m0 + row) * DIM + c + 4];
        bf8 pp;
#pragma unroll
        for (int j = 0; j < 4; ++j) {
            pp[j]     = f2bf(p0[j] + q0[j]);
            pp[4 + j] = f2bf(p1[j] + q1[j]);
        }
        *(bf8*)&lp[row][c] = pp;
    }
    if (t < 128) { sv1[t] = v1[t]; sv2[t] = v2[t]; }
    if (t < 16) { float rs = rsp[m0 + t] + rsp[NODES + m0 + t]; rsL[t] = rs; idL[t] = 1.f / (rs + 1e-8f); }
#pragma unroll
    for (int i = 0; i < 8; ++i) {
        int idx = t + i * 256;
        int nr = idx >> 4, c2 = (idx & 15) * 8;
        *(i32x4*)&lw1[nr][c2] = *(const i32x4*)&W1[(size_t)nr * DIM + c2];
        *(i32x4*)&lw2[nr][c2] = *(const i32x4*)&W2[(size_t)nr * DIM + c2];
    }
    __syncthreads();
    // score -> coeff (threads 0..127: 8 per row)
    if (t < 128) {
        int row = t >> 3, seg = t & 7;
        float id = idL[row];
        float s = 0.f;
#pragma unroll
        for (int j = 0; j < 16; ++j) {
            int c3 = seg * 16 + j;
            s += bf2f(lx[row][c3]) * sv1[c3] + bf2f(lp[row][c3]) * (sv2[c3] * id);
        }
        s += __shfl_xor(s, 1); s += __shfl_xor(s, 2); s += __shfl_xor(s, 4);
        if (seg == 0) {
            float sc = s + cc[0] + rsL[row] * cc[1] * id;
            sc = sc > 0.f ? sc : 0.2f * sc;
            coL[row] = 1.f / (1.f + __expf(-sc));
        }
    }
    f32x4 a1[2] = {{0.f, 0.f, 0.f, 0.f}, {0.f, 0.f, 0.f, 0.f}};
    f32x4 a2[2] = {{0.f, 0.f, 0.f, 0.f}, {0.f, 0.f, 0.f, 0.f}};
#pragma unroll
    for (int kk = 0; kk < 128; kk += 32) {
        bf8 xa = *(bf8*)&lx[lr][kk + q * 8];
        bf8 pa = *(bf8*)&lp[lr][kk + q * 8];
#pragma unroll
        for (int nf = 0; nf < 2; ++nf) {
            bf8 b1 = *(bf8*)&lw1[w * 32 + nf * 16 + lr][kk + q * 8];
            bf8 b2 = *(bf8*)&lw2[w * 32 + nf * 16 + lr][kk + q * 8];
            a1[nf] = __builtin_amdgcn_mfma_f32_16x16x32_bf16(xa, b1, a1[nf], 0, 0, 0);
            a2[nf] = __builtin_amdgcn_mfma_f32_16x16x32_bf16(pa, b2, a2[nf], 0, 0, 0);
        }
    }
    __syncthreads();   // coL visible
#pragma unroll
    for (int nf = 0; nf < 2; ++nf) {
        int col = w * 32 + nf * 16 + lr;
        float u1v = u1[col], u2v = u2[col];
        float mnv = 1e30f, mxv = -1e30f;
#pragma unroll
        for (int r = 0; r < 4; ++r) {
            int row = q * 4 + r;
            float cf = coL[row] * idL[row];
            float v = a1[nf][r] + cf * a2[nf][r] + u1v + rsL[row] * cf * u2v;
            outw[(size_t)(m0 + row) * DIM + col] = v;
            mnv = fminf(mnv, v); mxv = fmaxf(mxv, v);
        }
        mnv = fminf(mnv, __shfl_xor(mnv, 16)); mnv = fminf(mnv, __shfl_xor(mnv, 32));
        mxv = fmaxf(mxv, __shfl_xor(mxv, 16)); mxv = fmaxf(mxv, __shfl_xor(mxv, 32));
        if (l < 16) {
            atomicMin(&amin[col], fkey(mnv));
            atomicMax(&amax[col], fkey(mxv));
        }
    }
}

// ---- decode per-column atomic min/max -> smn, srv
__global__ __launch_bounds__(128) void k_red(const unsigned* __restrict__ amin, const unsigned* __restrict__ amax,
                                             float* __restrict__ smn, float* __restrict__ srv) {
    int t = threadIdx.x;
    float mn = fdec(amin[t]), mx = fdec(amax[t]);
    smn[t] = mn;
    srv[t] = 1.f / (mx - mn + 1e-8f);
}

// ---- final normalize + relu -> d_out (f32)
__global__ __launch_bounds__(256) void k_fin(const float* __restrict__ outp, const float* __restrict__ smn,
                                             const float* __restrict__ srv, float* __restrict__ dst) {
    int i = blockIdx.x * 256 + threadIdx.x;   // f32x4 index, 262144 total
    f32x4 v = *((const f32x4*)outp + i);
    int c0 = (i & 31) * 4;
    f32x4 mn = *(const f32x4*)&smn[c0], rv = *(const f32x4*)&srv[c0];
#pragma unroll
    for (int j = 0; j < 4; ++j) v[j] = fmaxf((v[j] - mn[j]) * rv[j], 0.f);
    *((f32x4*)dst + i) = v;
}

extern "C" void kernel_launch(void* const* d_in, const int* in_sizes, int n_in,
                              void* d_out, int out_size, void* d_ws, size_t ws_size,
                              hipStream_t stream) {
    const float* nodef = (const float*)d_in[0];
    const float* inc   = (const float*)d_in[1];
    const float* ef    = (const float*)d_in[2];
    const float* Wn    = (const float*)d_in[3];
    const float* bn    = (const float*)d_in[4];
    const float* We    = (const float*)d_in[5];
    const float* be    = (const float*)d_in[6];
    const float* Wa    = (const float*)d_in[7];
    const float* ba    = (const float*)d_in[8];
    const float* Wo    = (const float*)d_in[9];
    const float* bo    = (const float*)d_in[10];

    char* ws = (char*)d_ws;
    float*    Ppart  = (float*)(ws);                 // 2x8192x128 f32 = 8 MB
    float*    outp   = (float*)(ws + 8388608);       // 4 MB
    short*    xb0    = (short*)(ws + 12582912);      // 2 MB
    short*    efT    = (short*)(ws + 14680064);      // 1 MB
    short*    A1T    = (short*)(ws + 15728640);      // 128 KB
    short*    A2T    = (short*)(ws + 15859712);      // 128 KB
    float*    rspart = (float*)(ws + 15990784);      // 64 KB
    float*    v1     = (float*)(ws + 16056320);
    float*    v2     = (float*)(ws + 16058368);
    float*    u1     = (float*)(ws + 16060416);
    float*    u2     = (float*)(ws + 16062464);
    float*    cc     = (float*)(ws + 16064512);
    unsigned* amin   = (unsigned*)(ws + 16064576);   // 4x128
    unsigned* amax   = (unsigned*)(ws + 16066624);   // 4x128
    float*    smn    = (float*)(ws + 16068672);      // 4x128
    float*    srv    = (float*)(ws + 16070720);      // 4x128

    hipLaunchKernelGGL(k_prep_ef, dim3(128, 4), dim3(256), 0, stream, ef, efT);
    hipLaunchKernelGGL(k_prep_x, dim3(1024), dim3(256), 0, stream, nodef, xb0, amin, amax);
    hipLaunchKernelGGL(k_w, dim3(256), dim3(256), 0, stream, Wn, We, Wo, A1T, A2T);
    hipLaunchKernelGGL(k_wv, dim3(4), dim3(256), 0, stream, Wn, We, Wa, bn, be, ba, Wo, bo,
                       v1, v2, u1, u2, cc);
    hipLaunchKernelGGL(k1_pgemm, dim3(512), dim3(256), 0, stream, inc, efT, Ppart, rspart);

    for (int h = 0; h < NHEADS; ++h) {
        hipLaunchKernelGGL(k_out, dim3(512), dim3(256), 0, stream,
                           (h == 0) ? xb0 : (const short*)nullptr,
                           (h == 0) ? (const float*)nullptr : outp,
                           (h == 0) ? (const float*)nullptr : smn + (h - 1) * DIM,
                           (h == 0) ? (const float*)nullptr : srv + (h - 1) * DIM,
                           Ppart, rspart,
                           A1T + (size_t)h * DIM * DIM, A2T + (size_t)h * DIM * DIM,
                           v1 + h * DIM, v2 + h * DIM, cc + h * 2,
                           u1 + h * DIM, u2 + h * DIM,
                           amin + h * DIM, amax + h * DIM, outp);
        hipLaunchKernelGGL(k_red, dim3(1), dim3(128), 0, stream,
                           amin + h * DIM, amax + h * DIM, smn + h * DIM, srv + h * DIM);
    }
    hipLaunchKernelGGL(k_fin, dim3(1024), dim3(256), 0, stream, outp, smn + 3 * DIM, srv + 3 * DIM,
                       (float*)d_out);
}